// Round 2
// baseline (369.293 us; speedup 1.0000x reference)
//
#include <hip/hip_runtime.h>
#include <hip/hip_bf16.h>

// Problem: B=2, S=2048, C=U=1024, H=16, dh=64. I/O is FP32 (reference dtypes).
// Pipeline: cast X->bf16, transpose+cast W->bf16, QKV GEMM (bf16 MFMA, fp32 acc),
// flash attention (bf16 MFMA, fp32 softmax/acc, fp32 out), fp32 residual+LN.

typedef __bf16 bf16_t;
typedef __bf16 bf16x8 __attribute__((ext_vector_type(8)));
typedef __bf16 bf16x4 __attribute__((ext_vector_type(4)));
typedef float f32x4 __attribute__((ext_vector_type(4)));

constexpr int Bsz = 2;
constexpr int Seq = 2048;
constexpr int Cdim = 1024;   // == U
constexpr int Udim = 1024;
constexpr int Hn = 16;
constexpr int Dh = 64;
constexpr int Mrows = Bsz * Seq;          // 4096
constexpr int PerBatch = Seq * Udim;      // 2^21

// ---------------------------------------------------------------- cast X
__global__ __launch_bounds__(256)
void cast_x(const float* __restrict__ X, bf16_t* __restrict__ Xb)
{
    int i = blockIdx.x * 256 + threadIdx.x;     // over float4 groups, 1M total
    float4 v = ((const float4*)X)[i];
    bf16x4 o = { (bf16_t)v.x, (bf16_t)v.y, (bf16_t)v.z, (bf16_t)v.w };
    *(bf16x4*)(Xb + (size_t)i * 4) = o;
}

// ---------------------------------------------------------------- transpose W
// W[K=1024][N=1024] fp32 -> Wt[N][K] bf16; blockIdx.z selects q/k/v
__global__ void transpose_w(const float* __restrict__ Wq, const float* __restrict__ Wk,
                            const float* __restrict__ Wv,
                            bf16_t* __restrict__ Tq, bf16_t* __restrict__ Tk,
                            bf16_t* __restrict__ Tv)
{
    int z = blockIdx.z;
    const float* W = (z == 0) ? Wq : (z == 1) ? Wk : Wv;
    bf16_t* T = (z == 0) ? Tq : (z == 1) ? Tk : Tv;
    __shared__ bf16_t t[64][65];
    int x0 = blockIdx.x * 64, y0 = blockIdx.y * 64;
    int tx = threadIdx.x;
    for (int i = threadIdx.y; i < 64; i += 8)
        t[i][tx] = (bf16_t)W[(size_t)(y0 + i) * Cdim + x0 + tx];
    __syncthreads();
    for (int i = threadIdx.y; i < 64; i += 8)
        T[(size_t)(x0 + i) * Cdim + y0 + tx] = t[tx][i];
}

// ---------------------------------------------------------------- QKV GEMM
// C[4096][1024] = Xb @ W + bias (bias fp32), using Wt[N][K] bf16. Out bf16.
// 128x128 tile, 4 waves (2x2 of 64x64), BK=32, mfma 16x16x32 bf16.
__global__ __launch_bounds__(256)
void gemm_qkv(const bf16_t* __restrict__ X,
              const bf16_t* __restrict__ Wt0, const bf16_t* __restrict__ Wt1,
              const bf16_t* __restrict__ Wt2,
              const float* __restrict__ b0, const float* __restrict__ b1,
              const float* __restrict__ b2,
              bf16_t* __restrict__ O0, bf16_t* __restrict__ O1, bf16_t* __restrict__ O2)
{
    int z = blockIdx.z;
    const bf16_t* Wt = (z == 0) ? Wt0 : (z == 1) ? Wt1 : Wt2;
    const float* bias = (z == 0) ? b0 : (z == 1) ? b1 : b2;
    bf16_t* Og = (z == 0) ? O0 : (z == 1) ? O1 : O2;

    constexpr int Kd = 1024, Nd = 1024;
    __shared__ bf16_t As[128][40];   // +8 pad: 2-way bank alias only (free)
    __shared__ bf16_t Bs[128][40];

    int tid = threadIdx.x;
    int wave = tid >> 6, lane = tid & 63, quad = lane >> 4, l16 = lane & 15;
    int wm = (wave & 1) * 64, wn = (wave >> 1) * 64;
    int m0 = blockIdx.y * 128, n0 = blockIdx.x * 128;

    f32x4 acc[4][4] = {};

    int sr = tid >> 1, scol = (tid & 1) * 16;
    const bf16_t* Aptr = X + (size_t)(m0 + sr) * Kd + scol;
    const bf16_t* Bptr = Wt + (size_t)(n0 + sr) * Kd + scol;

    for (int k0 = 0; k0 < Kd; k0 += 32) {
        bf16x8 a0 = *(const bf16x8*)(Aptr + k0);
        bf16x8 a1 = *(const bf16x8*)(Aptr + k0 + 8);
        bf16x8 w0 = *(const bf16x8*)(Bptr + k0);
        bf16x8 w1 = *(const bf16x8*)(Bptr + k0 + 8);
        *(bf16x8*)&As[sr][scol] = a0;
        *(bf16x8*)&As[sr][scol + 8] = a1;
        *(bf16x8*)&Bs[sr][scol] = w0;
        *(bf16x8*)&Bs[sr][scol + 8] = w1;
        __syncthreads();

        bf16x8 af[4], bfr[4];
        for (int i = 0; i < 4; i++)
            af[i] = *(const bf16x8*)&As[wm + i * 16 + l16][quad * 8];
        for (int i = 0; i < 4; i++)
            bfr[i] = *(const bf16x8*)&Bs[wn + i * 16 + l16][quad * 8];
        for (int mt = 0; mt < 4; mt++)
            for (int nt = 0; nt < 4; nt++)
                acc[mt][nt] = __builtin_amdgcn_mfma_f32_16x16x32_bf16(
                    af[mt], bfr[nt], acc[mt][nt], 0, 0, 0);
        __syncthreads();
    }

    // epilogue: C/D layout col=lane&15, row=quad*4+reg (m89/m91 verified)
    for (int nt = 0; nt < 4; nt++) {
        int col = n0 + wn + nt * 16 + l16;
        float bv = bias[col];
        for (int mt = 0; mt < 4; mt++) {
            int row = m0 + wm + mt * 16 + quad * 4;
            for (int r = 0; r < 4; r++)
                Og[(size_t)(row + r) * Nd + col] = (bf16_t)(acc[mt][nt][r] + bv);
        }
    }
}

// ---------------------------------------------------------------- attention
// One block per (q-tile of 64, head, batch). 4 waves; each wave 16 q rows.
// Online softmax; causal mask; fp32 accumulators; P via LDS C->A layout.
// Output fp32.
__global__ __launch_bounds__(256)
void attn_kernel(const bf16_t* __restrict__ Q, const bf16_t* __restrict__ K,
                 const bf16_t* __restrict__ V, float* __restrict__ O)
{
    int qtile = blockIdx.x, h = blockIdx.y, b = blockIdx.z;
    int tid = threadIdx.x;
    int wave = tid >> 6, lane = tid & 63, quad = lane >> 4, l16 = lane & 15;

    __shared__ bf16_t Ks[64][72];      // K rows [kv][d]
    __shared__ bf16_t Vt[64][72];      // V transposed [d][kv]
    __shared__ bf16_t Pb[4][16][72];   // per-wave P [qrow][kv]

    int q0 = qtile * 64;
    const bf16_t* Qg = Q + (size_t)(b * Seq) * Udim + h * Dh;
    const bf16_t* Kg = K + (size_t)(b * Seq) * Udim + h * Dh;
    const bf16_t* Vg = V + (size_t)(b * Seq) * Udim + h * Dh;

    // Q fragments: A-layout A[m=lane&15][k=quad*8+j] (m120 verified); 2 k-steps
    int qr = q0 + wave * 16 + l16;
    bf16x8 qf0 = *(const bf16x8*)&Qg[(size_t)qr * Udim + quad * 8];
    bf16x8 qf1 = *(const bf16x8*)&Qg[(size_t)qr * Udim + 32 + quad * 8];

    f32x4 Oacc[4] = {};
    float mrow[4], lrow[4];
    for (int r = 0; r < 4; r++) { mrow[r] = -1e30f; lrow[r] = 0.0f; }

    for (int t = 0; t <= qtile; ++t) {
        int kv0 = t * 64;
        __syncthreads();   // prior iteration's LDS reads done
        {
            int r = tid >> 2, c = (tid & 3) * 16;
            bf16x8 k0v = *(const bf16x8*)&Kg[(size_t)(kv0 + r) * Udim + c];
            bf16x8 k1v = *(const bf16x8*)&Kg[(size_t)(kv0 + r) * Udim + c + 8];
            *(bf16x8*)&Ks[r][c] = k0v;
            *(bf16x8*)&Ks[r][c + 8] = k1v;
            bf16x8 v0v = *(const bf16x8*)&Vg[(size_t)(kv0 + r) * Udim + c];
            bf16x8 v1v = *(const bf16x8*)&Vg[(size_t)(kv0 + r) * Udim + c + 8];
            for (int j = 0; j < 8; j++) Vt[c + j][r] = v0v[j];
            for (int j = 0; j < 8; j++) Vt[c + 8 + j][r] = v1v[j];
        }
        __syncthreads();

        // S = Q K^T / 8 : B-operand B[k=d][n=kv] = Ks[kv][d] contiguous in d
        f32x4 sc[4];
        for (int nt = 0; nt < 4; nt++) {
            f32x4 zacc = {};
            bf16x8 kf0 = *(const bf16x8*)&Ks[nt * 16 + l16][quad * 8];
            bf16x8 kf1 = *(const bf16x8*)&Ks[nt * 16 + l16][32 + quad * 8];
            zacc = __builtin_amdgcn_mfma_f32_16x16x32_bf16(qf0, kf0, zacc, 0, 0, 0);
            zacc = __builtin_amdgcn_mfma_f32_16x16x32_bf16(qf1, kf1, zacc, 0, 0, 0);
            sc[nt] = zacc;
        }

        // online softmax over rows quad*4+r (C layout), cols 16 lanes x 4 ntiles
        int qbase = q0 + wave * 16 + quad * 4;
        float alpha[4];
        for (int r = 0; r < 4; r++) {
            float mx = -1e30f;
            for (int nt = 0; nt < 4; nt++) {
                float sv = sc[nt][r] * 0.125f;
                int kidx = kv0 + nt * 16 + l16;
                if (kidx > qbase + r) sv = -1e30f;   // causal
                sc[nt][r] = sv;
                mx = fmaxf(mx, sv);
            }
            for (int o = 1; o < 16; o <<= 1) mx = fmaxf(mx, __shfl_xor(mx, o));
            float mnew = fmaxf(mrow[r], mx);
            alpha[r] = __expf(mrow[r] - mnew);
            float s = 0.0f;
            for (int nt = 0; nt < 4; nt++) {
                float p = __expf(sc[nt][r] - mnew);
                sc[nt][r] = p;
                s += p;
            }
            for (int o = 1; o < 16; o <<= 1) s += __shfl_xor(s, o);
            lrow[r] = lrow[r] * alpha[r] + s;
            mrow[r] = mnew;
        }
        for (int dt = 0; dt < 4; dt++)
            for (int r = 0; r < 4; r++) Oacc[dt][r] *= alpha[r];

        // P: C layout -> LDS -> A layout
        for (int nt = 0; nt < 4; nt++)
            for (int r = 0; r < 4; r++)
                Pb[wave][quad * 4 + r][nt * 16 + l16] = (bf16_t)sc[nt][r];
        __syncthreads();

        // O += P V : B[k=kv][n=d] = Vt[d][kv] contiguous in kv
        bf16x8 pf0 = *(const bf16x8*)&Pb[wave][l16][quad * 8];
        bf16x8 pf1 = *(const bf16x8*)&Pb[wave][l16][32 + quad * 8];
        for (int dt = 0; dt < 4; dt++) {
            bf16x8 vf0 = *(const bf16x8*)&Vt[dt * 16 + l16][quad * 8];
            bf16x8 vf1 = *(const bf16x8*)&Vt[dt * 16 + l16][32 + quad * 8];
            Oacc[dt] = __builtin_amdgcn_mfma_f32_16x16x32_bf16(pf0, vf0, Oacc[dt], 0, 0, 0);
            Oacc[dt] = __builtin_amdgcn_mfma_f32_16x16x32_bf16(pf1, vf1, Oacc[dt], 0, 0, 0);
        }
    }

    float* Ogp = O + (size_t)(b * Seq) * Udim + h * Dh;
    int qb = q0 + wave * 16 + quad * 4;
    for (int dt = 0; dt < 4; dt++)
        for (int r = 0; r < 4; r++)
            Ogp[(size_t)(qb + r) * Udim + dt * 16 + l16] = Oacc[dt][r] / lrow[r];
}

// ---------------------------------------------------------------- LN stats
// resid = attn + input (both fp32); sum/sumsq per batch over S*U elements.
__global__ __launch_bounds__(256)
void ln_stats(const float* __restrict__ attn, const float* __restrict__ X,
              float* __restrict__ stats)
{
    int b = blockIdx.y;
    int base = b * PerBatch + blockIdx.x * 2048 + threadIdx.x * 8;
    float s = 0.0f, ss = 0.0f;
    for (int v = 0; v < 2; v++) {
        float4 a = *(const float4*)(attn + base + v * 4);
        float4 x = *(const float4*)(X + base + v * 4);
        float t0 = a.x + x.x, t1 = a.y + x.y, t2 = a.z + x.z, t3 = a.w + x.w;
        s += t0 + t1 + t2 + t3;
        ss += t0 * t0 + t1 * t1 + t2 * t2 + t3 * t3;
    }
    for (int o = 1; o < 64; o <<= 1) { s += __shfl_xor(s, o); ss += __shfl_xor(ss, o); }
    __shared__ float red[8];
    int wave = threadIdx.x >> 6, lane = threadIdx.x & 63;
    if (lane == 0) { red[wave] = s; red[4 + wave] = ss; }
    __syncthreads();
    if (threadIdx.x == 0) {
        atomicAdd(&stats[b], red[0] + red[1] + red[2] + red[3]);
        atomicAdd(&stats[2 + b], red[4] + red[5] + red[6] + red[7]);
    }
}

// ---------------------------------------------------------------- LN apply
__global__ __launch_bounds__(256)
void ln_norm(const float* __restrict__ attn, const float* __restrict__ X,
             const float* __restrict__ gamma, const float* __restrict__ beta,
             const float* __restrict__ stats, float* __restrict__ out)
{
    constexpr int TOT4 = Bsz * Seq * Udim / 4;   // 1M float4
    constexpr float invN = 1.0f / (float)PerBatch;
    float mu[2], inv[2];
    for (int b = 0; b < 2; b++) {
        float m = stats[b] * invN;
        float var = stats[2 + b] * invN - m * m;
        mu[b] = m;
        inv[b] = rsqrtf(var + 1e-5f);
    }
    for (int i = blockIdx.x * blockDim.x + threadIdx.x; i < TOT4;
         i += gridDim.x * blockDim.x) {
        int f = i * 4;
        int b = f >> 21;
        int su = f & (PerBatch - 1);
        float4 a = *(const float4*)(attn + f);
        float4 x = *(const float4*)(X + f);
        float4 g = *(const float4*)(gamma + su);
        float4 be = *(const float4*)(beta + su);
        float4 o;
        o.x = (a.x + x.x - mu[b]) * inv[b] * g.x + be.x;
        o.y = (a.y + x.y - mu[b]) * inv[b] * g.y + be.y;
        o.z = (a.z + x.z - mu[b]) * inv[b] * g.z + be.z;
        o.w = (a.w + x.w - mu[b]) * inv[b] * g.w + be.w;
        *(float4*)(out + f) = o;
    }
}

// ---------------------------------------------------------------- launch
extern "C" void kernel_launch(void* const* d_in, const int* in_sizes, int n_in,
                              void* d_out, int out_size, void* d_ws, size_t ws_size,
                              hipStream_t stream)
{
    const float* X     = (const float*)d_in[0];
    const float* Wq    = (const float*)d_in[1];
    const float* bq    = (const float*)d_in[2];
    const float* Wk    = (const float*)d_in[3];
    const float* bk    = (const float*)d_in[4];
    const float* Wv    = (const float*)d_in[5];
    const float* bv    = (const float*)d_in[6];
    const float* gamma = (const float*)d_in[7];
    const float* beta  = (const float*)d_in[8];
    float* out = (float*)d_out;

    char* ws = (char*)d_ws;
    size_t off = 0;
    auto alloc = [&](size_t bytes) -> void* {
        void* p = ws + off;
        off += (bytes + 255) & ~(size_t)255;
        return p;
    };
    bf16_t* Xb = (bf16_t*)alloc((size_t)Mrows * Cdim * 2);
    bf16_t* Tq = (bf16_t*)alloc((size_t)Cdim * Udim * 2);
    bf16_t* Tk = (bf16_t*)alloc((size_t)Cdim * Udim * 2);
    bf16_t* Tv = (bf16_t*)alloc((size_t)Cdim * Udim * 2);
    bf16_t* Qb = (bf16_t*)alloc((size_t)Mrows * Udim * 2);
    bf16_t* Kb = (bf16_t*)alloc((size_t)Mrows * Udim * 2);
    bf16_t* Vb = (bf16_t*)alloc((size_t)Mrows * Udim * 2);
    float*  Ab = (float*)alloc((size_t)Mrows * Udim * 4);
    float*  stats = (float*)alloc(4 * sizeof(float));

    hipMemsetAsync(stats, 0, 4 * sizeof(float), stream);
    cast_x<<<dim3(Mrows * Cdim / 4 / 256), 256, 0, stream>>>(X, Xb);
    transpose_w<<<dim3(16, 16, 3), dim3(64, 8), 0, stream>>>(Wq, Wk, Wv, Tq, Tk, Tv);
    gemm_qkv<<<dim3(8, 32, 3), 256, 0, stream>>>(Xb, Tq, Tk, Tv, bq, bk, bv, Qb, Kb, Vb);
    attn_kernel<<<dim3(Seq / 64, Hn, Bsz), 256, 0, stream>>>(Qb, Kb, Vb, Ab);
    ln_stats<<<dim3(1024, 2), 256, 0, stream>>>(Ab, X, stats);
    ln_norm<<<dim3(1024), 256, 0, stream>>>(Ab, X, gamma, beta, stats, out);
}